// Round 1
// baseline (542.887 us; speedup 1.0000x reference)
//
#include <hip/hip_runtime.h>
#include <math.h>

#define D_MODEL 1024
#define D_KEY 128
#define NSUB 256
#define NTOK 8192

// ---------------------------------------------------------------------------
// K1: q = x @ Wq^T   [8192,1024] x [256,1024]^T -> [8192,256]
// 64(tokens) x 64(cols) tile per block, BK=32, 4x4 register blocking.
// LDS tiles stored transposed [k][row] with stride 68 (float4-aligned, spreads
// banks: 68 % 32 = 4).
// ---------------------------------------------------------------------------
__global__ __launch_bounds__(256) void k_qproj(const float* __restrict__ x,
                                               const float* __restrict__ Wq,
                                               float* __restrict__ q) {
  __shared__ __align__(16) float xs[32][68];
  __shared__ __align__(16) float wqs[32][68];
  const int tid = threadIdx.x;
  const int n0 = blockIdx.x * 64;  // 4 col-tiles
  const int t0 = blockIdx.y * 64;  // 128 token-tiles
  const int tx = tid & 15, ty = tid >> 4;
  const int kvq = tid & 7;   // which float4 along k
  const int row = tid >> 3;  // 0..31
  float acc[4][4] = {};

  for (int kc = 0; kc < D_MODEL; kc += 32) {
#pragma unroll
    for (int rep = 0; rep < 2; rep++) {
      const int r = rep * 32 + row;
      const float4 vx = *(const float4*)&x[(size_t)(t0 + r) * D_MODEL + kc + kvq * 4];
      xs[kvq * 4 + 0][r] = vx.x; xs[kvq * 4 + 1][r] = vx.y;
      xs[kvq * 4 + 2][r] = vx.z; xs[kvq * 4 + 3][r] = vx.w;
      const float4 vw = *(const float4*)&Wq[(size_t)(n0 + r) * D_MODEL + kc + kvq * 4];
      wqs[kvq * 4 + 0][r] = vw.x; wqs[kvq * 4 + 1][r] = vw.y;
      wqs[kvq * 4 + 2][r] = vw.z; wqs[kvq * 4 + 3][r] = vw.w;
    }
    __syncthreads();
#pragma unroll
    for (int k = 0; k < 32; k++) {
      const float4 a = *(const float4*)&xs[k][tx * 4];
      const float4 b = *(const float4*)&wqs[k][ty * 4];
      acc[0][0] += a.x * b.x; acc[0][1] += a.x * b.y; acc[0][2] += a.x * b.z; acc[0][3] += a.x * b.w;
      acc[1][0] += a.y * b.x; acc[1][1] += a.y * b.y; acc[1][2] += a.y * b.z; acc[1][3] += a.y * b.w;
      acc[2][0] += a.z * b.x; acc[2][1] += a.z * b.y; acc[2][2] += a.z * b.z; acc[2][3] += a.z * b.w;
      acc[3][0] += a.w * b.x; acc[3][1] += a.w * b.y; acc[3][2] += a.w * b.z; acc[3][3] += a.w * b.w;
    }
    __syncthreads();
  }
#pragma unroll
  for (int i = 0; i < 4; i++) {
    float4 o = make_float4(acc[i][0], acc[i][1], acc[i][2], acc[i][3]);
    *(float4*)&q[(size_t)(t0 + tx * 4 + i) * NSUB + n0 + ty * 4] = o;
  }
}

// ---------------------------------------------------------------------------
// K2: per 16-token block: scores, top-8 a/b, 64-combo top-8, softmax,
// values gather + gate + residual output.
// ---------------------------------------------------------------------------
__global__ __launch_bounds__(256) void k_pkm(const float* __restrict__ x,
                                             const float* __restrict__ keys_a,
                                             const float* __restrict__ keys_b,
                                             const float* __restrict__ values,
                                             const float* __restrict__ gate_w,
                                             const float* __restrict__ gate_b,
                                             const float* __restrict__ q,
                                             float* __restrict__ out) {
  __shared__ __align__(16) float qs[16 * 256];   // q tile; reused as scores_a
  __shared__ __align__(16) float kas[256 * 20];  // keys_a chunk; reused as scores_b
  __shared__ __align__(16) float kbs[256 * 20];  // keys_b chunk
  __shared__ float ta_val[16][8]; __shared__ int ta_idx[16][8];
  __shared__ float tb_val[16][8]; __shared__ int tb_idx[16][8];
  __shared__ float fw[16][8];     __shared__ int fidx[16][8];
  __shared__ float gpart[4];

  const int tid = threadIdx.x;
  const int lane = tid & 63;
  const int wave = tid >> 6;
  const size_t tok0 = (size_t)blockIdx.x * 16;

  // ---- load q tile [16][256] (coalesced float4) ----
#pragma unroll
  for (int r = 0; r < 4; r++) {
    const int f4 = r * 256 + tid;
    const float4 v = *(const float4*)&q[tok0 * NSUB + (size_t)f4 * 4];
    *(float4*)&qs[f4 * 4] = v;
  }

  // ---- scores: thread n = tid owns columns scores_a[t][n], scores_b[t][n] ----
  float acca[16] = {};
  float accb[16] = {};
  for (int jc = 0; jc < 8; jc++) {  // 8 chunks of 16 along d_key
    __syncthreads();
#pragma unroll
    for (int r = 0; r < 4; r++) {
      const int f4 = r * 256 + tid;
      const int n = f4 >> 2, jv = f4 & 3;
      const float4 va = *(const float4*)&keys_a[(size_t)n * D_KEY + jc * 16 + jv * 4];
      *(float4*)&kas[n * 20 + jv * 4] = va;
      const float4 vb = *(const float4*)&keys_b[(size_t)n * D_KEY + jc * 16 + jv * 4];
      *(float4*)&kbs[n * 20 + jv * 4] = vb;
    }
    __syncthreads();
#pragma unroll
    for (int j4 = 0; j4 < 4; j4++) {
      const float4 ka = *(const float4*)&kas[tid * 20 + j4 * 4];
      const float4 kb = *(const float4*)&kbs[tid * 20 + j4 * 4];
#pragma unroll
      for (int t = 0; t < 16; t++) {
        const float4 qa = *(const float4*)&qs[t * 256 + jc * 16 + j4 * 4];
        const float4 qb = *(const float4*)&qs[t * 256 + 128 + jc * 16 + j4 * 4];
        acca[t] += qa.x * ka.x + qa.y * ka.y + qa.z * ka.z + qa.w * ka.w;
        accb[t] += qb.x * kb.x + qb.y * kb.y + qb.z * kb.z + qb.w * kb.w;
      }
    }
  }
  __syncthreads();
  float* sa = qs;   // reuse
  float* sb = kas;  // reuse (needs 4096 floats, region has 5120)
#pragma unroll
  for (int t = 0; t < 16; t++) {
    sa[t * 256 + tid] = acca[t];
    sb[t * 256 + tid] = accb[t];
  }
  __syncthreads();

  // ---- top-k: wave handles tokens wave*4 .. wave*4+3 ----
  for (int tt = 0; tt < 4; tt++) {
    const int t = wave * 4 + tt;
    float sva[4], svb[4];
#pragma unroll
    for (int c = 0; c < 4; c++) {
      sva[c] = sa[t * 256 + lane + 64 * c];
      svb[c] = sb[t * 256 + lane + 64 * c];
    }
    // top-8 of scores_a (tie -> lowest index, matching lax.top_k)
    for (int sel = 0; sel < 8; sel++) {
      float bv = -INFINITY; int bi = 0x7fffffff;
#pragma unroll
      for (int c = 0; c < 4; c++) {
        if (sva[c] > bv) { bv = sva[c]; bi = lane + 64 * c; }
      }
#pragma unroll
      for (int off = 32; off >= 1; off >>= 1) {
        const float ov = __shfl_xor(bv, off);
        const int oi = __shfl_xor(bi, off);
        if (ov > bv || (ov == bv && oi < bi)) { bv = ov; bi = oi; }
      }
      if (lane == (bi & 63)) sva[bi >> 6] = -INFINITY;
      if (lane == 0) { ta_val[t][sel] = bv; ta_idx[t][sel] = bi; }
    }
    // top-8 of scores_b
    for (int sel = 0; sel < 8; sel++) {
      float bv = -INFINITY; int bi = 0x7fffffff;
#pragma unroll
      for (int c = 0; c < 4; c++) {
        if (svb[c] > bv) { bv = svb[c]; bi = lane + 64 * c; }
      }
#pragma unroll
      for (int off = 32; off >= 1; off >>= 1) {
        const float ov = __shfl_xor(bv, off);
        const int oi = __shfl_xor(bi, off);
        if (ov > bv || (ov == bv && oi < bi)) { bv = ov; bi = oi; }
      }
      if (lane == (bi & 63)) svb[bi >> 6] = -INFINITY;
      if (lane == 0) { tb_val[t][sel] = bv; tb_idx[t][sel] = bi; }
    }
    // combine: lane l -> candidate (i = l>>3, j = l&7), row-major like reference
    float cv = ta_val[t][lane >> 3] + tb_val[t][lane & 7];
    for (int sel = 0; sel < 8; sel++) {
      float bv = cv; int bi = lane;
#pragma unroll
      for (int off = 32; off >= 1; off >>= 1) {
        const float ov = __shfl_xor(bv, off);
        const int oi = __shfl_xor(bi, off);
        if (ov > bv || (ov == bv && oi < bi)) { bv = ov; bi = oi; }
      }
      if (lane == bi) cv = -INFINITY;
      if (lane == 0) {
        fw[t][sel] = bv;
        fidx[t][sel] = ta_idx[t][bi >> 3] * NSUB + tb_idx[t][bi & 7];
      }
    }
    // softmax over the 8 (fw[t][0] is the max since selection is descending)
    if (lane < 8) {
      const float v = fw[t][lane];
      const float m = fw[t][0];
      float e = __expf(v - m);
      float s = e;
      s += __shfl_xor(s, 1); s += __shfl_xor(s, 2); s += __shfl_xor(s, 4);
      fw[t][lane] = e / s;
    }
  }
  __syncthreads();

  // ---- gather + gate + residual output ----
  const float4 gw4 = *(const float4*)&gate_w[tid * 4];
  const float gb = gate_b[0];
  for (int t = 0; t < 16; t++) {
    const float4 x4 = *(const float4*)&x[(tok0 + t) * D_MODEL + tid * 4];
    float gp = x4.x * gw4.x + x4.y * gw4.y + x4.z * gw4.z + x4.w * gw4.w;
#pragma unroll
    for (int off = 32; off >= 1; off >>= 1) gp += __shfl_xor(gp, off);
    if (lane == 0) gpart[wave] = gp;
    __syncthreads();
    float g = gpart[0] + gpart[1] + gpart[2] + gpart[3] + gb;
    g = 1.0f / (1.0f + __expf(-g));
    float4 acc = make_float4(0.f, 0.f, 0.f, 0.f);
#pragma unroll
    for (int k = 0; k < 8; k++) {
      const float w = fw[t][k];
      const int idx = fidx[t][k];
      const float4 v4 = *(const float4*)&values[(size_t)idx * D_MODEL + tid * 4];
      acc.x += w * v4.x; acc.y += w * v4.y; acc.z += w * v4.z; acc.w += w * v4.w;
    }
    float4 o;
    o.x = x4.x + g * acc.x; o.y = x4.y + g * acc.y;
    o.z = x4.z + g * acc.z; o.w = x4.w + g * acc.w;
    *(float4*)&out[(tok0 + t) * D_MODEL + tid * 4] = o;
    __syncthreads();  // gpart reused next token
  }
}

extern "C" void kernel_launch(void* const* d_in, const int* in_sizes, int n_in,
                              void* d_out, int out_size, void* d_ws, size_t ws_size,
                              hipStream_t stream) {
  const float* x = (const float*)d_in[0];
  const float* keys_a = (const float*)d_in[1];
  const float* keys_b = (const float*)d_in[2];
  const float* values = (const float*)d_in[3];
  const float* Wq = (const float*)d_in[4];
  const float* gate_w = (const float*)d_in[5];
  const float* gate_b = (const float*)d_in[6];
  float* out = (float*)d_out;
  float* q = (float*)d_ws;  // 8192*256*4 = 8 MB scratch

  k_qproj<<<dim3(4, 128), 256, 0, stream>>>(x, Wq, q);
  k_pkm<<<NTOK / 16, 256, 0, stream>>>(x, keys_a, keys_b, values, gate_w, gate_b, q, out);
}

// Round 3
// 515.235 us; speedup vs baseline: 1.0537x; 1.0537x over previous
//
#include <hip/hip_runtime.h>
#include <math.h>

#define D_MODEL 1024
#define D_KEY 128
#define NSUB 256
#define NTOK 8192

typedef __attribute__((ext_vector_type(8))) short bf16x8;
typedef __attribute__((ext_vector_type(4))) float f32x4;

__device__ __forceinline__ unsigned short f2bf(float f) {
  union { float f; unsigned int u; } v; v.f = f;
  return (unsigned short)((v.u + 0x7fffu + ((v.u >> 16) & 1u)) >> 16);
}
__device__ __forceinline__ float bf2f(unsigned short u) {
  union { unsigned int u; float f; } v; v.u = ((unsigned int)u) << 16;
  return v.f;
}

// ---------------------------------------------------------------------------
// K0: M_T[c][d] = sum_j Wq[joff+j][d] * keys[c%256][j]   (bf16 out, [512][1024])
// Fuses the q-projection into the key matrices: scores = x @ M.
// Grid 128 blocks x 4 c-rows each. Blocks 0..63 = a-side, 64..127 = b-side.
// ---------------------------------------------------------------------------
__global__ __launch_bounds__(256) void k_prep(const float* __restrict__ Wq,
                                              const float* __restrict__ keys_a,
                                              const float* __restrict__ keys_b,
                                              unsigned short* __restrict__ Mt) {
  __shared__ float ks[4][128];
  const int tid = threadIdx.x;
  const int c0 = blockIdx.x * 4;
  const float* kk = (c0 < 256) ? keys_a : keys_b;
  const int rbase = c0 & 255;
  const int joff = (c0 < 256) ? 0 : 128;
  if (tid < 128) {
    const int r = tid >> 5, f = tid & 31;
    *(float4*)&ks[r][f * 4] = *(const float4*)&kk[(size_t)(rbase + r) * 128 + f * 4];
  }
  __syncthreads();
  const int d0 = tid * 4;
  float acc[4][4] = {};
  for (int j = 0; j < 128; j++) {
    const float4 wv = *(const float4*)&Wq[(size_t)(joff + j) * D_MODEL + d0];
#pragma unroll
    for (int r = 0; r < 4; r++) {
      const float kj = ks[r][j];
      acc[r][0] += wv.x * kj; acc[r][1] += wv.y * kj;
      acc[r][2] += wv.z * kj; acc[r][3] += wv.w * kj;
    }
  }
#pragma unroll
  for (int r = 0; r < 4; r++) {
    ushort4 o;
    o.x = f2bf(acc[r][0]); o.y = f2bf(acc[r][1]);
    o.z = f2bf(acc[r][2]); o.w = f2bf(acc[r][3]);
    *(ushort4*)&Mt[(size_t)(c0 + r) * D_MODEL + d0] = o;
  }
}

// ---------------------------------------------------------------------------
// K1: scores[t][c] = sum_d x[t][d] * M_T[c][d]  via bf16 MFMA 16x16x32.
// Tile 64 tok x 128 col, BK=32, 4 waves each 32x64. Grid (4, 128) = 512 blocks.
// Output bf16 [8192][512].
// ---------------------------------------------------------------------------
__global__ __launch_bounds__(256) void k_scores(const float* __restrict__ x,
                                                const unsigned short* __restrict__ Mt,
                                                unsigned short* __restrict__ scores) {
  __shared__ __align__(16) short Asd[64 * 32];   // [tok][k] bf16
  __shared__ __align__(16) short Bsd[128 * 32];  // [col][k] bf16
  const int tid = threadIdx.x;
  const int t0 = blockIdx.y * 64;
  const int c0 = blockIdx.x * 128;
  // staging coords
  const int arow = tid >> 2, aseg = tid & 3;  // 64 rows x 4 segs of 8 floats
  const int brow = tid >> 1, bhalf = tid & 1; // 128 rows x 2 halves of 16 bf16
  const float* xp = x + (size_t)(t0 + arow) * D_MODEL + aseg * 8;
  const unsigned short* mp = Mt + (size_t)(c0 + brow) * D_MODEL + bhalf * 16;
  // wave coords
  const int l = tid & 63, w = tid >> 6;
  const int rw0 = (w & 1) * 32;   // token offset in tile
  const int cw0 = (w >> 1) * 64;  // col offset in tile
  const int fr = l & 15, q = l >> 4;

  f32x4 acc[2][4];
#pragma unroll
  for (int mi = 0; mi < 2; mi++)
#pragma unroll
    for (int ni = 0; ni < 4; ni++) acc[mi][ni] = (f32x4){0.f, 0.f, 0.f, 0.f};

  for (int kc = 0; kc < D_MODEL; kc += 32) {
    const float4 a0 = *(const float4*)(xp + kc);
    const float4 a1 = *(const float4*)(xp + kc + 4);
    bf16x8 pk;
    pk[0] = (short)f2bf(a0.x); pk[1] = (short)f2bf(a0.y);
    pk[2] = (short)f2bf(a0.z); pk[3] = (short)f2bf(a0.w);
    pk[4] = (short)f2bf(a1.x); pk[5] = (short)f2bf(a1.y);
    pk[6] = (short)f2bf(a1.z); pk[7] = (short)f2bf(a1.w);
    *(bf16x8*)&Asd[arow * 32 + aseg * 8] = pk;
    const uint4 b0 = *(const uint4*)(mp + kc);
    const uint4 b1 = *(const uint4*)(mp + kc + 8);
    *(uint4*)&Bsd[brow * 32 + bhalf * 16] = b0;
    *(uint4*)&Bsd[brow * 32 + bhalf * 16 + 8] = b1;
    __syncthreads();
    bf16x8 af[2], bfr[4];
#pragma unroll
    for (int mi = 0; mi < 2; mi++)
      af[mi] = *(const bf16x8*)&Asd[(rw0 + mi * 16 + fr) * 32 + q * 8];
#pragma unroll
    for (int ni = 0; ni < 4; ni++)
      bfr[ni] = *(const bf16x8*)&Bsd[(cw0 + ni * 16 + fr) * 32 + q * 8];
#pragma unroll
    for (int mi = 0; mi < 2; mi++)
#pragma unroll
      for (int ni = 0; ni < 4; ni++)
        acc[mi][ni] = __builtin_amdgcn_mfma_f32_16x16x32_bf16(af[mi], bfr[ni], acc[mi][ni], 0, 0, 0);
    __syncthreads();
  }
  // C/D layout: col = lane&15, row = (lane>>4)*4 + reg
#pragma unroll
  for (int mi = 0; mi < 2; mi++)
#pragma unroll
    for (int ni = 0; ni < 4; ni++)
#pragma unroll
      for (int r = 0; r < 4; r++) {
        const int row = t0 + rw0 + mi * 16 + q * 4 + r;
        const int col = c0 + cw0 + ni * 16 + fr;
        scores[(size_t)row * 512 + col] = f2bf(acc[mi][ni][r]);
      }
}

// ---------------------------------------------------------------------------
// K2: one wave per token. Scores (bf16) -> top8 a/b -> 64-combo top8 ->
// softmax -> gather/gate/residual. No LDS, no __syncthreads.
// ---------------------------------------------------------------------------
__global__ __launch_bounds__(256) void k_topk(const float* __restrict__ x,
                                              const float* __restrict__ values,
                                              const float* __restrict__ gate_w,
                                              const float* __restrict__ gate_b,
                                              const unsigned short* __restrict__ scores,
                                              float* __restrict__ out) {
  const int tid = threadIdx.x;
  const int lane = tid & 63;
  const int wave = tid >> 6;
  const size_t t = (size_t)blockIdx.x * 4 + wave;

  const unsigned short* srow = scores + t * 512;
  const ushort4 ra = *(const ushort4*)&srow[lane * 4];
  const ushort4 rb = *(const ushort4*)&srow[256 + lane * 4];
  float sva[4] = {bf2f(ra.x), bf2f(ra.y), bf2f(ra.z), bf2f(ra.w)};
  float svb[4] = {bf2f(rb.x), bf2f(rb.y), bf2f(rb.z), bf2f(rb.w)};

  float tav[8], tbv[8];
  int tai[8], tbi[8];
  // top-8 of a-scores (tie -> lowest index, matching lax.top_k)
#pragma unroll
  for (int sel = 0; sel < 8; sel++) {
    float bv = sva[0]; int bi = lane * 4;
#pragma unroll
    for (int c = 1; c < 4; c++)
      if (sva[c] > bv) { bv = sva[c]; bi = lane * 4 + c; }
#pragma unroll
    for (int off = 32; off >= 1; off >>= 1) {
      const float ov = __shfl_xor(bv, off);
      const int oi = __shfl_xor(bi, off);
      if (ov > bv || (ov == bv && oi < bi)) { bv = ov; bi = oi; }
    }
    tav[sel] = bv; tai[sel] = bi;
    if ((bi >> 2) == lane) sva[bi & 3] = -INFINITY;
  }
  // top-8 of b-scores
#pragma unroll
  for (int sel = 0; sel < 8; sel++) {
    float bv = svb[0]; int bi = lane * 4;
#pragma unroll
    for (int c = 1; c < 4; c++)
      if (svb[c] > bv) { bv = svb[c]; bi = lane * 4 + c; }
#pragma unroll
    for (int off = 32; off >= 1; off >>= 1) {
      const float ov = __shfl_xor(bv, off);
      const int oi = __shfl_xor(bi, off);
      if (ov > bv || (ov == bv && oi < bi)) { bv = ov; bi = oi; }
    }
    tbv[sel] = bv; tbi[sel] = bi;
    if ((bi >> 2) == lane) svb[bi & 3] = -INFINITY;
  }
  // 64 combined candidates: lane = i*8 + j (row-major, matches reference flat order)
  float cv = tav[lane >> 3] + tbv[lane & 7];
  float fv[8]; int fidx[8];
#pragma unroll
  for (int sel = 0; sel < 8; sel++) {
    float bv = cv; int bi = lane;
#pragma unroll
    for (int off = 32; off >= 1; off >>= 1) {
      const float ov = __shfl_xor(bv, off);
      const int oi = __shfl_xor(bi, off);
      if (ov > bv || (ov == bv && oi < bi)) { bv = ov; bi = oi; }
    }
    fv[sel] = bv;
    fidx[sel] = tai[bi >> 3] * NSUB + tbi[bi & 7];
    if (lane == bi) cv = -INFINITY;
  }
  // softmax (fv[0] is max; every lane computes all 8 redundantly)
  float wgt[8];
  {
    float s = 0.f;
#pragma unroll
    for (int k = 0; k < 8; k++) { wgt[k] = __expf(fv[k] - fv[0]); s += wgt[k]; }
    const float inv = 1.0f / s;
#pragma unroll
    for (int k = 0; k < 8; k++) wgt[k] *= inv;
  }

  // gate + gather + residual. Lane owns 16 floats (4 float4) of d.
  const size_t base = t * D_MODEL + lane * 16;
  float4 xv[4], gw[4];
#pragma unroll
  for (int u = 0; u < 4; u++) {
    xv[u] = *(const float4*)&x[base + u * 4];
    gw[u] = *(const float4*)&gate_w[lane * 16 + u * 4];
  }
  float gp = 0.f;
#pragma unroll
  for (int u = 0; u < 4; u++)
    gp += xv[u].x * gw[u].x + xv[u].y * gw[u].y + xv[u].z * gw[u].z + xv[u].w * gw[u].w;
#pragma unroll
  for (int off = 32; off >= 1; off >>= 1) gp += __shfl_xor(gp, off);
  const float g = 1.0f / (1.0f + __expf(-(gp + gate_b[0])));

  float4 facc[4] = {{0, 0, 0, 0}, {0, 0, 0, 0}, {0, 0, 0, 0}, {0, 0, 0, 0}};
#pragma unroll
  for (int k = 0; k < 8; k++) {
    const float wk = wgt[k];
    const float* vrow = values + (size_t)fidx[k] * D_MODEL + lane * 16;
#pragma unroll
    for (int u = 0; u < 4; u++) {
      const float4 v4 = *(const float4*)&vrow[u * 4];
      facc[u].x += wk * v4.x; facc[u].y += wk * v4.y;
      facc[u].z += wk * v4.z; facc[u].w += wk * v4.w;
    }
  }
#pragma unroll
  for (int u = 0; u < 4; u++) {
    float4 o;
    o.x = xv[u].x + g * facc[u].x; o.y = xv[u].y + g * facc[u].y;
    o.z = xv[u].z + g * facc[u].z; o.w = xv[u].w + g * facc[u].w;
    *(float4*)&out[base + u * 4] = o;
  }
}

extern "C" void kernel_launch(void* const* d_in, const int* in_sizes, int n_in,
                              void* d_out, int out_size, void* d_ws, size_t ws_size,
                              hipStream_t stream) {
  const float* x = (const float*)d_in[0];
  const float* keys_a = (const float*)d_in[1];
  const float* keys_b = (const float*)d_in[2];
  const float* values = (const float*)d_in[3];
  const float* Wq = (const float*)d_in[4];
  const float* gate_w = (const float*)d_in[5];
  const float* gate_b = (const float*)d_in[6];
  float* out = (float*)d_out;

  unsigned short* scores = (unsigned short*)d_ws;                  // 8 MB bf16 [8192][512]
  unsigned short* Mt = (unsigned short*)((char*)d_ws + (size_t)NTOK * 512 * 2);  // 1 MB bf16 [512][1024]

  k_prep<<<128, 256, 0, stream>>>(Wq, keys_a, keys_b, Mt);
  k_scores<<<dim3(4, 128), 256, 0, stream>>>(x, Mt, scores);
  k_topk<<<NTOK / 4, 256, 0, stream>>>(x, values, gate_w, gate_b, scores, out);
}

// Round 4
// 464.074 us; speedup vs baseline: 1.1698x; 1.1102x over previous
//
#include <hip/hip_runtime.h>
#include <math.h>

#define D_MODEL 1024
#define D_KEY 128
#define NSUB 256
#define NTOK 8192

typedef __attribute__((ext_vector_type(8))) short bf16x8;
typedef __attribute__((ext_vector_type(4))) float f32x4;

__device__ __forceinline__ unsigned short f2bf(float f) {
  union { float f; unsigned int u; } v; v.f = f;
  return (unsigned short)((v.u + 0x7fffu + ((v.u >> 16) & 1u)) >> 16);
}
__device__ __forceinline__ float bf2f(unsigned short u) {
  union { unsigned int u; float f; } v; v.u = ((unsigned int)u) << 16;
  return v.f;
}

// ---------------------------------------------------------------------------
// K0: M_T[c][d] = sum_j Wq[joff+j][d] * keys[c%256][j]   (bf16 out, [512][1024])
// ---------------------------------------------------------------------------
__global__ __launch_bounds__(256) void k_prep(const float* __restrict__ Wq,
                                              const float* __restrict__ keys_a,
                                              const float* __restrict__ keys_b,
                                              unsigned short* __restrict__ Mt) {
  __shared__ float ks[4][128];
  const int tid = threadIdx.x;
  const int c0 = blockIdx.x * 4;
  const float* kk = (c0 < 256) ? keys_a : keys_b;
  const int rbase = c0 & 255;
  const int joff = (c0 < 256) ? 0 : 128;
  if (tid < 128) {
    const int r = tid >> 5, f = tid & 31;
    *(float4*)&ks[r][f * 4] = *(const float4*)&kk[(size_t)(rbase + r) * 128 + f * 4];
  }
  __syncthreads();
  const int d0 = tid * 4;
  float acc[4][4] = {};
  for (int j = 0; j < 128; j++) {
    const float4 wv = *(const float4*)&Wq[(size_t)(joff + j) * D_MODEL + d0];
#pragma unroll
    for (int r = 0; r < 4; r++) {
      const float kj = ks[r][j];
      acc[r][0] += wv.x * kj; acc[r][1] += wv.y * kj;
      acc[r][2] += wv.z * kj; acc[r][3] += wv.w * kj;
    }
  }
#pragma unroll
  for (int r = 0; r < 4; r++) {
    ushort4 o;
    o.x = f2bf(acc[r][0]); o.y = f2bf(acc[r][1]);
    o.z = f2bf(acc[r][2]); o.w = f2bf(acc[r][3]);
    *(ushort4*)&Mt[(size_t)(c0 + r) * D_MODEL + d0] = o;
  }
}

// ---------------------------------------------------------------------------
// K1: scores[t][c] = sum_d x[t][d] * M_T[c][d]  via bf16 MFMA 16x16x32.
// Tile 64 tok x 128 col, BK=32, 4 waves each 32x64. Grid (4, 128).
// ---------------------------------------------------------------------------
__global__ __launch_bounds__(256) void k_scores(const float* __restrict__ x,
                                                const unsigned short* __restrict__ Mt,
                                                unsigned short* __restrict__ scores) {
  __shared__ __align__(16) short Asd[64 * 32];   // [tok][k] bf16
  __shared__ __align__(16) short Bsd[128 * 32];  // [col][k] bf16
  const int tid = threadIdx.x;
  const int t0 = blockIdx.y * 64;
  const int c0 = blockIdx.x * 128;
  const int arow = tid >> 2, aseg = tid & 3;
  const int brow = tid >> 1, bhalf = tid & 1;
  const float* xp = x + (size_t)(t0 + arow) * D_MODEL + aseg * 8;
  const unsigned short* mp = Mt + (size_t)(c0 + brow) * D_MODEL + bhalf * 16;
  const int l = tid & 63, w = tid >> 6;
  const int rw0 = (w & 1) * 32;
  const int cw0 = (w >> 1) * 64;
  const int fr = l & 15, q = l >> 4;

  f32x4 acc[2][4];
#pragma unroll
  for (int mi = 0; mi < 2; mi++)
#pragma unroll
    for (int ni = 0; ni < 4; ni++) acc[mi][ni] = (f32x4){0.f, 0.f, 0.f, 0.f};

  for (int kc = 0; kc < D_MODEL; kc += 32) {
    const float4 a0 = *(const float4*)(xp + kc);
    const float4 a1 = *(const float4*)(xp + kc + 4);
    bf16x8 pk;
    pk[0] = (short)f2bf(a0.x); pk[1] = (short)f2bf(a0.y);
    pk[2] = (short)f2bf(a0.z); pk[3] = (short)f2bf(a0.w);
    pk[4] = (short)f2bf(a1.x); pk[5] = (short)f2bf(a1.y);
    pk[6] = (short)f2bf(a1.z); pk[7] = (short)f2bf(a1.w);
    *(bf16x8*)&Asd[arow * 32 + aseg * 8] = pk;
    const uint4 b0 = *(const uint4*)(mp + kc);
    const uint4 b1 = *(const uint4*)(mp + kc + 8);
    *(uint4*)&Bsd[brow * 32 + bhalf * 16] = b0;
    *(uint4*)&Bsd[brow * 32 + bhalf * 16 + 8] = b1;
    __syncthreads();
    bf16x8 af[2], bfr[4];
#pragma unroll
    for (int mi = 0; mi < 2; mi++)
      af[mi] = *(const bf16x8*)&Asd[(rw0 + mi * 16 + fr) * 32 + q * 8];
#pragma unroll
    for (int ni = 0; ni < 4; ni++)
      bfr[ni] = *(const bf16x8*)&Bsd[(cw0 + ni * 16 + fr) * 32 + q * 8];
#pragma unroll
    for (int mi = 0; mi < 2; mi++)
#pragma unroll
      for (int ni = 0; ni < 4; ni++)
        acc[mi][ni] = __builtin_amdgcn_mfma_f32_16x16x32_bf16(af[mi], bfr[ni], acc[mi][ni], 0, 0, 0);
    __syncthreads();
  }
#pragma unroll
  for (int mi = 0; mi < 2; mi++)
#pragma unroll
    for (int ni = 0; ni < 4; ni++)
#pragma unroll
      for (int r = 0; r < 4; r++) {
        const int row = t0 + rw0 + mi * 16 + q * 4 + r;
        const int col = c0 + cw0 + ni * 16 + fr;
        scores[(size_t)row * 512 + col] = f2bf(acc[mi][ni][r]);
      }
}

// ---------------------------------------------------------------------------
// K2: one wave per token. scores -> top8 a/b -> 64-combo top8 -> softmax ->
// write (idx, weight) pairs. No gather here: keeps the serial shuffle chain
// off the gather's critical path.
// ---------------------------------------------------------------------------
__global__ __launch_bounds__(256) void k_topk_sel(const unsigned short* __restrict__ scores,
                                                  float* __restrict__ wout,
                                                  int* __restrict__ iout) {
  const int tid = threadIdx.x;
  const int lane = tid & 63;
  const int wave = tid >> 6;
  const size_t t = (size_t)blockIdx.x * 4 + wave;

  const unsigned short* srow = scores + t * 512;
  const ushort4 ra = *(const ushort4*)&srow[lane * 4];
  const ushort4 rb = *(const ushort4*)&srow[256 + lane * 4];
  float sva[4] = {bf2f(ra.x), bf2f(ra.y), bf2f(ra.z), bf2f(ra.w)};
  float svb[4] = {bf2f(rb.x), bf2f(rb.y), bf2f(rb.z), bf2f(rb.w)};

  float tav[8], tbv[8];
  int tai[8], tbi[8];
#pragma unroll
  for (int sel = 0; sel < 8; sel++) {
    float bv = sva[0]; int bi = lane * 4;
#pragma unroll
    for (int c = 1; c < 4; c++)
      if (sva[c] > bv) { bv = sva[c]; bi = lane * 4 + c; }
#pragma unroll
    for (int off = 32; off >= 1; off >>= 1) {
      const float ov = __shfl_xor(bv, off);
      const int oi = __shfl_xor(bi, off);
      if (ov > bv || (ov == bv && oi < bi)) { bv = ov; bi = oi; }
    }
    tav[sel] = bv; tai[sel] = bi;
    if ((bi >> 2) == lane) sva[bi & 3] = -INFINITY;
  }
#pragma unroll
  for (int sel = 0; sel < 8; sel++) {
    float bv = svb[0]; int bi = lane * 4;
#pragma unroll
    for (int c = 1; c < 4; c++)
      if (svb[c] > bv) { bv = svb[c]; bi = lane * 4 + c; }
#pragma unroll
    for (int off = 32; off >= 1; off >>= 1) {
      const float ov = __shfl_xor(bv, off);
      const int oi = __shfl_xor(bi, off);
      if (ov > bv || (ov == bv && oi < bi)) { bv = ov; bi = oi; }
    }
    tbv[sel] = bv; tbi[sel] = bi;
    if ((bi >> 2) == lane) svb[bi & 3] = -INFINITY;
  }
  // 64 combined candidates: lane = i*8 + j (row-major flat order)
  float cv = tav[lane >> 3] + tbv[lane & 7];
  float fv[8]; int fidx[8];
#pragma unroll
  for (int sel = 0; sel < 8; sel++) {
    float bv = cv; int bi = lane;
#pragma unroll
    for (int off = 32; off >= 1; off >>= 1) {
      const float ov = __shfl_xor(bv, off);
      const int oi = __shfl_xor(bi, off);
      if (ov > bv || (ov == bv && oi < bi)) { bv = ov; bi = oi; }
    }
    fv[sel] = bv;
    fidx[sel] = tai[bi >> 3] * NSUB + tbi[bi & 7];
    if (lane == bi) cv = -INFINITY;
  }
  // softmax (fv[0] is the max; uniform across lanes)
  float wgt[8];
  float s = 0.f;
#pragma unroll
  for (int k = 0; k < 8; k++) { wgt[k] = __expf(fv[k] - fv[0]); s += wgt[k]; }
  const float inv = 1.0f / s;
#pragma unroll
  for (int k = 0; k < 8; k++) wgt[k] *= inv;

  if (lane == 0) {
    *(float4*)&wout[t * 8] = make_float4(wgt[0], wgt[1], wgt[2], wgt[3]);
    *(float4*)&wout[t * 8 + 4] = make_float4(wgt[4], wgt[5], wgt[6], wgt[7]);
    *(int4*)&iout[t * 8] = make_int4(fidx[0], fidx[1], fidx[2], fidx[3]);
    *(int4*)&iout[t * 8 + 4] = make_int4(fidx[4], fidx[5], fidx[6], fidx[7]);
  }
}

// ---------------------------------------------------------------------------
// K3: one 256-thread block per token. Full-row coalesced gather of 8 value
// rows + gate (from the x row we load anyway) + residual.
// ---------------------------------------------------------------------------
__global__ __launch_bounds__(256) void k_gather(const float* __restrict__ x,
                                                const float* __restrict__ values,
                                                const float* __restrict__ gate_w,
                                                const float* __restrict__ gate_b,
                                                const float* __restrict__ win,
                                                const int* __restrict__ iin,
                                                float* __restrict__ out) {
  __shared__ float swgt[8];
  __shared__ int sidx[8];
  __shared__ float gpart[4];
  const int tid = threadIdx.x;
  const int lane = tid & 63;
  const int wave = tid >> 6;
  const size_t t = blockIdx.x;

  if (tid < 2) *(float4*)&swgt[tid * 4] = *(const float4*)&win[t * 8 + tid * 4];
  else if (tid < 4) *(int4*)&sidx[(tid - 2) * 4] = *(const int4*)&iin[t * 8 + (tid - 2) * 4];

  const float4 x4 = *(const float4*)&x[t * D_MODEL + tid * 4];
  const float4 gw4 = *(const float4*)&gate_w[tid * 4];
  float gp = x4.x * gw4.x + x4.y * gw4.y + x4.z * gw4.z + x4.w * gw4.w;
#pragma unroll
  for (int off = 32; off >= 1; off >>= 1) gp += __shfl_xor(gp, off);
  if (lane == 0) gpart[wave] = gp;
  __syncthreads();

  const float g = 1.0f / (1.0f + __expf(-(gpart[0] + gpart[1] + gpart[2] + gpart[3] + gate_b[0])));
  float4 acc = make_float4(0.f, 0.f, 0.f, 0.f);
#pragma unroll
  for (int k = 0; k < 8; k++) {
    const float wk = swgt[k];
    const float4 v4 = *(const float4*)&values[(size_t)sidx[k] * D_MODEL + tid * 4];
    acc.x += wk * v4.x; acc.y += wk * v4.y;
    acc.z += wk * v4.z; acc.w += wk * v4.w;
  }
  float4 o;
  o.x = x4.x + g * acc.x; o.y = x4.y + g * acc.y;
  o.z = x4.z + g * acc.z; o.w = x4.w + g * acc.w;
  *(float4*)&out[t * D_MODEL + tid * 4] = o;
}

extern "C" void kernel_launch(void* const* d_in, const int* in_sizes, int n_in,
                              void* d_out, int out_size, void* d_ws, size_t ws_size,
                              hipStream_t stream) {
  const float* x = (const float*)d_in[0];
  const float* keys_a = (const float*)d_in[1];
  const float* keys_b = (const float*)d_in[2];
  const float* values = (const float*)d_in[3];
  const float* Wq = (const float*)d_in[4];
  const float* gate_w = (const float*)d_in[5];
  const float* gate_b = (const float*)d_in[6];
  float* out = (float*)d_out;

  char* ws = (char*)d_ws;
  unsigned short* scores = (unsigned short*)ws;                       // 8 MB
  unsigned short* Mt = (unsigned short*)(ws + (size_t)NTOK * 512 * 2);  // 1 MB
  float* wbuf = (float*)(ws + 9u * 1024 * 1024);                      // 256 KB
  int* ibuf = (int*)(ws + 9u * 1024 * 1024 + 256 * 1024);             // 256 KB

  k_prep<<<128, 256, 0, stream>>>(Wq, keys_a, keys_b, Mt);
  k_scores<<<dim3(4, 128), 256, 0, stream>>>(x, Mt, scores);
  k_topk_sel<<<NTOK / 4, 256, 0, stream>>>(scores, wbuf, ibuf);
  k_gather<<<NTOK, 256, 0, stream>>>(x, values, gate_w, gate_b, wbuf, ibuf, out);
}